// Round 4
// baseline (1530.599 us; speedup 1.0000x reference)
//
#include <hip/hip_runtime.h>
#include <stdint.h>

#define BB 16
#define NN 4096
#define CC 64
#define NPOINT 1024
#define KK 32
#define F1 64
#define F2 64
#define F3 128

// ---------------- farthest point sampling ----------------
// one block per batch; points live in registers; exact np float32 arithmetic:
// d = ((dx*dx + dy*dy) + dz*dz) with no FMA contraction; argmax first-occurrence.
// Outputs exact fp32 centroids straight into d_out (output 0).
#define FPS_T 512
#define PPT (NN / FPS_T)   // 8

__global__ __launch_bounds__(FPS_T)
void fps_kernel(const float* __restrict__ xyz,
                float* __restrict__ out_xyz) {
    const int b = blockIdx.x;
    const int tid = threadIdx.x;
    const float* __restrict__ xb = xyz + (size_t)b * (NN * 3);

    float px[PPT], py[PPT], pz[PPT], dist[PPT];
#pragma unroll
    for (int t = 0; t < PPT; ++t) {
        int p = tid + t * FPS_T;
        px[t] = xb[p * 3 + 0];
        py[t] = xb[p * 3 + 1];
        pz[t] = xb[p * 3 + 2];
        dist[t] = 1e10f;
    }

    __shared__ float cent[3];
    __shared__ unsigned long long wred[FPS_T / 64];
    if (tid == 0) { cent[0] = px[0]; cent[1] = py[0]; cent[2] = pz[0]; }
    __syncthreads();

    float* xout = out_xyz + (size_t)b * NPOINT * 3;

    for (int i = 0; i < NPOINT; ++i) {
        float cx = cent[0], cy = cent[1], cz = cent[2];
        if (tid == 0) {
            xout[i * 3 + 0] = cx;
            xout[i * 3 + 1] = cy;
            xout[i * 3 + 2] = cz;
        }
        float bd = -1.0f; int bp = 0;
#pragma unroll
        for (int t = 0; t < PPT; ++t) {
            float dx = __fsub_rn(px[t], cx);
            float dy = __fsub_rn(py[t], cy);
            float dz = __fsub_rn(pz[t], cz);
            float d  = __fadd_rn(__fadd_rn(__fmul_rn(dx, dx), __fmul_rn(dy, dy)),
                                 __fmul_rn(dz, dz));
            float nd = fminf(dist[t], d);
            dist[t] = nd;
            if (nd > bd) { bd = nd; bp = tid + t * FPS_T; }  // strict > : first occurrence
        }
        // pack (dist_bits << 32) | (N-1-idx): max => larger dist, tie => smaller idx
        unsigned long long key = (((unsigned long long)__float_as_uint(bd)) << 32)
                               | (unsigned int)(NN - 1 - bp);
#pragma unroll
        for (int off = 32; off > 0; off >>= 1) {
            unsigned long long o = __shfl_xor(key, off, 64);
            if (o > key) key = o;
        }
        const int lane = tid & 63, wid = tid >> 6;
        if (lane == 0) wred[wid] = key;
        __syncthreads();
        unsigned long long best = wred[0];
#pragma unroll
        for (int w = 1; w < FPS_T / 64; ++w) {
            unsigned long long o = wred[w];
            if (o > best) best = o;
        }
        int bi = (NN - 1) - (int)(best & 0xffffffffu);
        if ((bi & (FPS_T - 1)) == tid) {
            int t = bi >> 9;   // FPS_T = 512
            cent[0] = px[t]; cent[1] = py[t]; cent[2] = pz[t];
        }
        __syncthreads();
    }
}

// ---------------- fused ball query + gather + MLP + maxpool ----------------
// one 256-thread block per (b, s) group; all fp32
__global__ __launch_bounds__(256)
void group_mlp_kernel(const float* __restrict__ xyz,
                      const float* __restrict__ points,
                      const float* __restrict__ w0, const float* __restrict__ b0,
                      const float* __restrict__ w1, const float* __restrict__ b1,
                      const float* __restrict__ w2, const float* __restrict__ b2,
                      const float* __restrict__ out_xyz,
                      float* __restrict__ out_points) {
    const int g = blockIdx.x;
    const int b = g >> 10;            // NPOINT = 1024
    const int tid = threadIdx.x;
    const int f = tid & 63;
    const int wid = tid >> 6;

    __shared__ float gbuf[KK][68];    // 32 x (67 + pad)
    __shared__ float hbuf[KK][F1];    // 32 x 64
    __shared__ float pmax[4][F3];     // per-wave partial max
    __shared__ int nbr[KK];

    // exact fp32 centroid (output 0 holds exact selected coordinates)
    const float cx = out_xyz[(size_t)g * 3 + 0];
    const float cy = out_xyz[(size_t)g * 3 + 1];
    const float cz = out_xyz[(size_t)g * 3 + 2];

    // ---- phase A: ball query on wave 0 ----
    if (tid < 64) {
        const float* __restrict__ xb = xyz + (size_t)b * (NN * 3);
        int cnt = 0;
        for (int base = 0; base < NN; base += 64) {
            int p = base + tid;
            float x = xb[p * 3 + 0];
            float y = xb[p * 3 + 1];
            float z = xb[p * 3 + 2];
            float dx = __fsub_rn(cx, x);   // square identical either direction
            float dy = __fsub_rn(cy, y);
            float dz = __fsub_rn(cz, z);
            float d2 = __fadd_rn(__fadd_rn(__fmul_rn(dx, dx), __fmul_rn(dy, dy)),
                                 __fmul_rn(dz, dz));
            bool in = (d2 <= 0.04f);       // float32(0.2*0.2) == 0.04f (jnp/np both f32-compare)
            unsigned long long m = __ballot(in);
            int pos = cnt + (int)__popcll(m & ((1ull << tid) - 1ull));
            if (in && pos < KK) nbr[pos] = p;
            cnt += (int)__popcll(m);
            if (cnt >= KK) break;
        }
        if (cnt < KK) {
            int first = nbr[0];            // centroid itself guarantees cnt >= 1
            if (tid >= cnt && tid < KK) nbr[tid] = first;
        }
    }
    __syncthreads();

    // ---- phase B: gather (points + relative xyz) into LDS ----
    {
        const float* __restrict__ pb = points + (size_t)b * NN * CC;
#pragma unroll
        for (int m = 0; m < 8; ++m) {
            int k = wid + 4 * m;
            int idx = nbr[k] & (NN - 1);   // hardened: can never fault
            gbuf[k][f] = pb[(size_t)idx * CC + f];
        }
        if (tid < 96) {
            int k = tid & 31, q = tid >> 5;
            int idx = nbr[k] & (NN - 1);
            float v = xyz[((size_t)b * NN + idx) * 3 + q];
            float cq = (q == 0) ? cx : ((q == 1) ? cy : cz);
            gbuf[k][CC + q] = __fsub_rn(v, cq);
        }
    }
    __syncthreads();

    float acc[8];

    // ---- layer 1: 67 -> 64, gbuf -> hbuf ----
#pragma unroll
    for (int m = 0; m < 8; ++m) acc[m] = 0.0f;
#pragma unroll 4
    for (int c4 = 0; c4 < 64; c4 += 4) {
        float wv0 = w0[(c4 + 0) * F1 + f];
        float wv1 = w0[(c4 + 1) * F1 + f];
        float wv2 = w0[(c4 + 2) * F1 + f];
        float wv3 = w0[(c4 + 3) * F1 + f];
#pragma unroll
        for (int m = 0; m < 8; ++m) {
            float4 gv = *(const float4*)&gbuf[wid + 4 * m][c4];
            acc[m] = fmaf(gv.x, wv0, acc[m]);
            acc[m] = fmaf(gv.y, wv1, acc[m]);
            acc[m] = fmaf(gv.z, wv2, acc[m]);
            acc[m] = fmaf(gv.w, wv3, acc[m]);
        }
    }
    {
        float wv0 = w0[64 * F1 + f];
        float wv1 = w0[65 * F1 + f];
        float wv2 = w0[66 * F1 + f];
#pragma unroll
        for (int m = 0; m < 8; ++m) {
            int k = wid + 4 * m;
            acc[m] = fmaf(gbuf[k][64], wv0, acc[m]);
            acc[m] = fmaf(gbuf[k][65], wv1, acc[m]);
            acc[m] = fmaf(gbuf[k][66], wv2, acc[m]);
        }
    }
    {
        float bb = b0[f];
#pragma unroll
        for (int m = 0; m < 8; ++m)
            hbuf[wid + 4 * m][f] = fmaxf(acc[m] + bb, 0.0f);
    }
    __syncthreads();

    // ---- layer 2: 64 -> 64, hbuf -> gbuf (reuse, stride 68) ----
#pragma unroll
    for (int m = 0; m < 8; ++m) acc[m] = 0.0f;
#pragma unroll 4
    for (int c4 = 0; c4 < 64; c4 += 4) {
        float wv0 = w1[(c4 + 0) * F2 + f];
        float wv1 = w1[(c4 + 1) * F2 + f];
        float wv2 = w1[(c4 + 2) * F2 + f];
        float wv3 = w1[(c4 + 3) * F2 + f];
#pragma unroll
        for (int m = 0; m < 8; ++m) {
            float4 gv = *(const float4*)&hbuf[wid + 4 * m][c4];
            acc[m] = fmaf(gv.x, wv0, acc[m]);
            acc[m] = fmaf(gv.y, wv1, acc[m]);
            acc[m] = fmaf(gv.z, wv2, acc[m]);
            acc[m] = fmaf(gv.w, wv3, acc[m]);
        }
    }
    {
        float bb = b1[f];
#pragma unroll
        for (int m = 0; m < 8; ++m)
            gbuf[wid + 4 * m][f] = fmaxf(acc[m] + bb, 0.0f);
    }
    __syncthreads();

    // ---- layer 3: 64 -> 128, gbuf -> maxpool ----
    float a0[8], a1[8];
#pragma unroll
    for (int m = 0; m < 8; ++m) { a0[m] = 0.0f; a1[m] = 0.0f; }
#pragma unroll 2
    for (int c4 = 0; c4 < 64; c4 += 4) {
        float w00 = w2[(c4 + 0) * F3 + f], w10 = w2[(c4 + 0) * F3 + f + 64];
        float w01 = w2[(c4 + 1) * F3 + f], w11 = w2[(c4 + 1) * F3 + f + 64];
        float w02 = w2[(c4 + 2) * F3 + f], w12 = w2[(c4 + 2) * F3 + f + 64];
        float w03 = w2[(c4 + 3) * F3 + f], w13 = w2[(c4 + 3) * F3 + f + 64];
#pragma unroll
        for (int m = 0; m < 8; ++m) {
            float4 gv = *(const float4*)&gbuf[wid + 4 * m][c4];
            a0[m] = fmaf(gv.x, w00, a0[m]);  a1[m] = fmaf(gv.x, w10, a1[m]);
            a0[m] = fmaf(gv.y, w01, a0[m]);  a1[m] = fmaf(gv.y, w11, a1[m]);
            a0[m] = fmaf(gv.z, w02, a0[m]);  a1[m] = fmaf(gv.z, w12, a1[m]);
            a0[m] = fmaf(gv.w, w03, a0[m]);  a1[m] = fmaf(gv.w, w13, a1[m]);
        }
    }
    {
        float pm0 = -1e30f, pm1 = -1e30f;
#pragma unroll
        for (int m = 0; m < 8; ++m) {
            pm0 = fmaxf(pm0, a0[m]);
            pm1 = fmaxf(pm1, a1[m]);
        }
        pmax[wid][f] = pm0;
        pmax[wid][f + 64] = pm1;
    }
    __syncthreads();
    if (tid < F3) {
        float v = fmaxf(fmaxf(pmax[0][tid], pmax[1][tid]),
                        fmaxf(pmax[2][tid], pmax[3][tid]));
        v = fmaxf(v + b2[tid], 0.0f);   // relu(max+b) == max(relu(+b)) (monotone)
        out_points[(size_t)g * F3 + tid] = v;
    }
}

extern "C" void kernel_launch(void* const* d_in, const int* in_sizes, int n_in,
                              void* d_out, int out_size, void* d_ws, size_t ws_size,
                              hipStream_t stream) {
    const float* xyz    = (const float*)d_in[0];
    const float* points = (const float*)d_in[1];
    const float* w0 = (const float*)d_in[2];
    const float* b0 = (const float*)d_in[3];
    const float* w1 = (const float*)d_in[4];
    const float* b1 = (const float*)d_in[5];
    const float* w2 = (const float*)d_in[6];
    const float* b2 = (const float*)d_in[7];

    float* out_xyz    = (float*)d_out;
    float* out_points = out_xyz + (size_t)BB * NPOINT * 3;

    fps_kernel<<<BB, FPS_T, 0, stream>>>(xyz, out_xyz);
    group_mlp_kernel<<<BB * NPOINT, 256, 0, stream>>>(xyz, points,
                                                      w0, b0, w1, b1, w2, b2,
                                                      out_xyz, out_points);
}

// Round 5
// 1076.945 us; speedup vs baseline: 1.4212x; 1.4212x over previous
//
#include <hip/hip_runtime.h>
#include <stdint.h>

#define BB 16
#define NN 4096
#define CC 64
#define NPOINT 1024
#define KK 32
#define F1 64
#define F2 64
#define F3 128

// ---------------- DPP 64-lane max-reduce helpers ----------------
// row_shr:n = 0x110|n ; row_bcast15 = 0x142 ; row_bcast31 = 0x143
// After the 6-step sequence lane 63 holds the wave-wide max.
#if defined(__has_builtin)
#if __has_builtin(__builtin_amdgcn_update_dpp)
#define HAS_DPP 1
#endif
#endif

#ifdef HAS_DPP
template <int CTRL>
__device__ __forceinline__ unsigned long long dpp_move64(unsigned long long k) {
    int lo = __builtin_amdgcn_update_dpp(0, (int)(unsigned)k,         CTRL, 0xF, 0xF, false);
    int hi = __builtin_amdgcn_update_dpp(0, (int)(unsigned)(k >> 32), CTRL, 0xF, 0xF, false);
    return ((unsigned long long)(unsigned)hi << 32) | (unsigned)lo;
}
__device__ __forceinline__ unsigned long long wave_max_key(unsigned long long key) {
    unsigned long long o;
    o = dpp_move64<0x111>(key); if (o > key) key = o;   // row_shr:1
    o = dpp_move64<0x112>(key); if (o > key) key = o;   // row_shr:2
    o = dpp_move64<0x114>(key); if (o > key) key = o;   // row_shr:4
    o = dpp_move64<0x118>(key); if (o > key) key = o;   // row_shr:8  -> row maxes at 15/31/47/63
    o = dpp_move64<0x142>(key); if (o > key) key = o;   // row_bcast15 -> lane31, lane63 pair maxes
    o = dpp_move64<0x143>(key); if (o > key) key = o;   // row_bcast31 -> lane63 full max
    return key;                                         // valid in lane 63
}
#else
__device__ __forceinline__ unsigned long long wave_max_key(unsigned long long key) {
#pragma unroll
    for (int off = 32; off > 0; off >>= 1) {
        unsigned long long o = __shfl_xor(key, off, 64);
        if (o > key) key = o;
    }
    return key;   // valid in all lanes (incl. 63)
}
#endif

// ---------------- farthest point sampling ----------------
// one block per batch; points in registers + LDS mirror; exact np float32:
// d = ((dx*dx + dy*dy) + dz*dz), no FMA contraction; argmax first-occurrence.
// Single barrier per iteration (ping-pong partials, centroid fetched from LDS
// by every thread); zero global stores inside the loop.
#define FPS_T 512
#define PPT (NN / FPS_T)   // 8

__global__ __launch_bounds__(FPS_T)
void fps_kernel(const float* __restrict__ xyz,
                float* __restrict__ out_xyz) {
    const int b = blockIdx.x;
    const int tid = threadIdx.x;
    const int lane = tid & 63, wid = tid >> 6;
    const float* __restrict__ xb = xyz + (size_t)b * (NN * 3);

    __shared__ float xs[NN], ys[NN], zs[NN];            // 48 KB
    __shared__ unsigned long long wred[2][FPS_T / 64];

    float px[PPT], py[PPT], pz[PPT], dist[PPT];
#pragma unroll
    for (int t = 0; t < PPT; ++t) {
        int p = tid + t * FPS_T;
        px[t] = xb[p * 3 + 0];
        py[t] = xb[p * 3 + 1];
        pz[t] = xb[p * 3 + 2];
        xs[p] = px[t]; ys[p] = py[t]; zs[p] = pz[t];
        dist[t] = 1e10f;
    }
    __syncthreads();

    float cx = xs[0], cy = ys[0], cz = zs[0];   // centroid 0 = point 0
    int r0 = 0, r1 = 0;                          // recorded winner idx for slots tid, tid+512

    for (int i = 0; i < NPOINT; ++i) {
        float bd = -1.0f; int bp = 0;
#pragma unroll
        for (int t = 0; t < PPT; ++t) {
            float dx = __fsub_rn(px[t], cx);
            float dy = __fsub_rn(py[t], cy);
            float dz = __fsub_rn(pz[t], cz);
            float d  = __fadd_rn(__fadd_rn(__fmul_rn(dx, dx), __fmul_rn(dy, dy)),
                                 __fmul_rn(dz, dz));
            float nd = fminf(dist[t], d);
            dist[t] = nd;
            if (nd > bd) { bd = nd; bp = tid + t * FPS_T; }  // strict > : first occurrence
        }
        // pack (dist_bits << 32) | (N-1-idx): max => larger dist, tie => smaller idx
        unsigned long long key = (((unsigned long long)__float_as_uint(bd)) << 32)
                               | (unsigned int)(NN - 1 - bp);
        key = wave_max_key(key);
        if (lane == 63) wred[i & 1][wid] = key;
        __syncthreads();

        unsigned long long best = wred[i & 1][0];
#pragma unroll
        for (int w = 1; w < FPS_T / 64; ++w) {
            unsigned long long o = wred[i & 1][w];
            if (o > best) best = o;
        }
        int bi = (NN - 1) - (int)(best & 0xffffffffu);
        // slot i+1's centroid is point bi; record it on its owner thread
        int slot = i + 1;
        if (slot < NPOINT && (slot & (FPS_T - 1)) == tid) {
            if (slot & FPS_T) r1 = bi; else r0 = bi;
        }
        cx = xs[bi]; cy = ys[bi]; cz = zs[bi];   // LDS broadcast (no 2nd barrier)
    }

    // epilogue: thread tid writes output slots tid and tid+512
    float* xo = out_xyz + (size_t)b * NPOINT * 3;
    xo[tid * 3 + 0] = xs[r0];
    xo[tid * 3 + 1] = ys[r0];
    xo[tid * 3 + 2] = zs[r0];
    xo[(tid + FPS_T) * 3 + 0] = xs[r1];
    xo[(tid + FPS_T) * 3 + 1] = ys[r1];
    xo[(tid + FPS_T) * 3 + 2] = zs[r1];
}

// ---------------- fused ball query + gather + MLP + maxpool ----------------
// one 256-thread block per (b, s) group; all fp32
__global__ __launch_bounds__(256)
void group_mlp_kernel(const float* __restrict__ xyz,
                      const float* __restrict__ points,
                      const float* __restrict__ w0, const float* __restrict__ b0,
                      const float* __restrict__ w1, const float* __restrict__ b1,
                      const float* __restrict__ w2, const float* __restrict__ b2,
                      const float* __restrict__ out_xyz,
                      float* __restrict__ out_points) {
    const int g = blockIdx.x;
    const int b = g >> 10;            // NPOINT = 1024
    const int tid = threadIdx.x;
    const int f = tid & 63;
    const int wid = tid >> 6;

    __shared__ float gbuf[KK][68];    // 32 x (67 + pad)
    __shared__ float hbuf[KK][F1];    // 32 x 64
    __shared__ float pmax[4][F3];     // per-wave partial max
    __shared__ unsigned long long cmask[NN / 64];   // per-chunk in-radius ballot
    __shared__ int nbr[KK];

    // exact fp32 centroid (output 0 holds exact selected coordinates)
    const float cx = out_xyz[(size_t)g * 3 + 0];
    const float cy = out_xyz[(size_t)g * 3 + 1];
    const float cz = out_xyz[(size_t)g * 3 + 2];

    // ---- phase A1: all 4 waves scan all 4096 points (no serial chain) ----
    {
        const float* __restrict__ xb = xyz + (size_t)b * (NN * 3);
#pragma unroll 4
        for (int j = 0; j < 16; ++j) {
            int chunk = wid * 16 + j;
            int p = chunk * 64 + f;
            float x = xb[p * 3 + 0];
            float y = xb[p * 3 + 1];
            float z = xb[p * 3 + 2];
            float dx = __fsub_rn(cx, x);   // square identical either direction
            float dy = __fsub_rn(cy, y);
            float dz = __fsub_rn(cz, z);
            float d2 = __fadd_rn(__fadd_rn(__fmul_rn(dx, dx), __fmul_rn(dy, dy)),
                                 __fmul_rn(dz, dz));
            unsigned long long m = __ballot(d2 <= 0.04f);  // float32(0.2*0.2)
            if (f == 0) cmask[chunk] = m;
        }
    }
    __syncthreads();

    // ---- phase A2: wave 0 — ordered compaction of the 32 smallest indices ----
    if (tid < 64) {
        unsigned long long m = cmask[tid];
        int cnt = (int)__popcll(m);
        int v = cnt;                                  // inclusive prefix scan
#pragma unroll
        for (int off = 1; off < 64; off <<= 1) {
            int u = __shfl_up(v, off, 64);
            if (tid >= off) v += u;
        }
        int excl = v - cnt;
        int total = __shfl(v, 63, 64);
        // emit this chunk's in-radius indices at ranks excl..excl+cnt-1
        unsigned long long mm = m;
        int r = excl;
        while (mm && r < KK) {
            int bpos = __ffsll(mm) - 1;
            mm &= mm - 1;
            nbr[r++] = tid * 64 + bpos;
        }
        // pad with the first in-radius index (centroid guarantees total >= 1)
        if (total < KK) {
            unsigned long long nz = __ballot(cnt > 0);
            int fchunk = __ffsll(nz) - 1;
            unsigned long long fm = cmask[fchunk];
            int first = fchunk * 64 + __ffsll(fm) - 1;
            if (tid >= total && tid < KK) nbr[tid] = first;
        }
    }
    __syncthreads();

    // ---- phase B: gather (points + relative xyz) into LDS ----
    {
        const float* __restrict__ pb = points + (size_t)b * NN * CC;
#pragma unroll
        for (int m = 0; m < 8; ++m) {
            int k = wid + 4 * m;
            int idx = nbr[k] & (NN - 1);   // hardened: can never fault
            gbuf[k][f] = pb[(size_t)idx * CC + f];
        }
        if (tid < 96) {
            int k = tid & 31, q = tid >> 5;
            int idx = nbr[k] & (NN - 1);
            float v = xyz[((size_t)b * NN + idx) * 3 + q];
            float cq = (q == 0) ? cx : ((q == 1) ? cy : cz);
            gbuf[k][CC + q] = __fsub_rn(v, cq);
        }
    }
    __syncthreads();

    float acc[8];

    // ---- layer 1: 67 -> 64, gbuf -> hbuf ----
#pragma unroll
    for (int m = 0; m < 8; ++m) acc[m] = 0.0f;
#pragma unroll 4
    for (int c4 = 0; c4 < 64; c4 += 4) {
        float wv0 = w0[(c4 + 0) * F1 + f];
        float wv1 = w0[(c4 + 1) * F1 + f];
        float wv2 = w0[(c4 + 2) * F1 + f];
        float wv3 = w0[(c4 + 3) * F1 + f];
#pragma unroll
        for (int m = 0; m < 8; ++m) {
            float4 gv = *(const float4*)&gbuf[wid + 4 * m][c4];
            acc[m] = fmaf(gv.x, wv0, acc[m]);
            acc[m] = fmaf(gv.y, wv1, acc[m]);
            acc[m] = fmaf(gv.z, wv2, acc[m]);
            acc[m] = fmaf(gv.w, wv3, acc[m]);
        }
    }
    {
        float wv0 = w0[64 * F1 + f];
        float wv1 = w0[65 * F1 + f];
        float wv2 = w0[66 * F1 + f];
#pragma unroll
        for (int m = 0; m < 8; ++m) {
            int k = wid + 4 * m;
            acc[m] = fmaf(gbuf[k][64], wv0, acc[m]);
            acc[m] = fmaf(gbuf[k][65], wv1, acc[m]);
            acc[m] = fmaf(gbuf[k][66], wv2, acc[m]);
        }
    }
    {
        float bb = b0[f];
#pragma unroll
        for (int m = 0; m < 8; ++m)
            hbuf[wid + 4 * m][f] = fmaxf(acc[m] + bb, 0.0f);
    }
    __syncthreads();

    // ---- layer 2: 64 -> 64, hbuf -> gbuf (reuse, stride 68) ----
#pragma unroll
    for (int m = 0; m < 8; ++m) acc[m] = 0.0f;
#pragma unroll 4
    for (int c4 = 0; c4 < 64; c4 += 4) {
        float wv0 = w1[(c4 + 0) * F2 + f];
        float wv1 = w1[(c4 + 1) * F2 + f];
        float wv2 = w1[(c4 + 2) * F2 + f];
        float wv3 = w1[(c4 + 3) * F2 + f];
#pragma unroll
        for (int m = 0; m < 8; ++m) {
            float4 gv = *(const float4*)&hbuf[wid + 4 * m][c4];
            acc[m] = fmaf(gv.x, wv0, acc[m]);
            acc[m] = fmaf(gv.y, wv1, acc[m]);
            acc[m] = fmaf(gv.z, wv2, acc[m]);
            acc[m] = fmaf(gv.w, wv3, acc[m]);
        }
    }
    {
        float bb = b1[f];
#pragma unroll
        for (int m = 0; m < 8; ++m)
            gbuf[wid + 4 * m][f] = fmaxf(acc[m] + bb, 0.0f);
    }
    __syncthreads();

    // ---- layer 3: 64 -> 128, gbuf -> maxpool ----
    float a0[8], a1[8];
#pragma unroll
    for (int m = 0; m < 8; ++m) { a0[m] = 0.0f; a1[m] = 0.0f; }
#pragma unroll 2
    for (int c4 = 0; c4 < 64; c4 += 4) {
        float w00 = w2[(c4 + 0) * F3 + f], w10 = w2[(c4 + 0) * F3 + f + 64];
        float w01 = w2[(c4 + 1) * F3 + f], w11 = w2[(c4 + 1) * F3 + f + 64];
        float w02 = w2[(c4 + 2) * F3 + f], w12 = w2[(c4 + 2) * F3 + f + 64];
        float w03 = w2[(c4 + 3) * F3 + f], w13 = w2[(c4 + 3) * F3 + f + 64];
#pragma unroll
        for (int m = 0; m < 8; ++m) {
            float4 gv = *(const float4*)&gbuf[wid + 4 * m][c4];
            a0[m] = fmaf(gv.x, w00, a0[m]);  a1[m] = fmaf(gv.x, w10, a1[m]);
            a0[m] = fmaf(gv.y, w01, a0[m]);  a1[m] = fmaf(gv.y, w11, a1[m]);
            a0[m] = fmaf(gv.z, w02, a0[m]);  a1[m] = fmaf(gv.z, w12, a1[m]);
            a0[m] = fmaf(gv.w, w03, a0[m]);  a1[m] = fmaf(gv.w, w13, a1[m]);
        }
    }
    {
        float pm0 = -1e30f, pm1 = -1e30f;
#pragma unroll
        for (int m = 0; m < 8; ++m) {
            pm0 = fmaxf(pm0, a0[m]);
            pm1 = fmaxf(pm1, a1[m]);
        }
        pmax[wid][f] = pm0;
        pmax[wid][f + 64] = pm1;
    }
    __syncthreads();
    if (tid < F3) {
        float v = fmaxf(fmaxf(pmax[0][tid], pmax[1][tid]),
                        fmaxf(pmax[2][tid], pmax[3][tid]));
        v = fmaxf(v + b2[tid], 0.0f);   // relu(max+b) == max(relu(+b)) (monotone)
        out_points[(size_t)g * F3 + tid] = v;
    }
}

extern "C" void kernel_launch(void* const* d_in, const int* in_sizes, int n_in,
                              void* d_out, int out_size, void* d_ws, size_t ws_size,
                              hipStream_t stream) {
    const float* xyz    = (const float*)d_in[0];
    const float* points = (const float*)d_in[1];
    const float* w0 = (const float*)d_in[2];
    const float* b0 = (const float*)d_in[3];
    const float* w1 = (const float*)d_in[4];
    const float* b1 = (const float*)d_in[5];
    const float* w2 = (const float*)d_in[6];
    const float* b2 = (const float*)d_in[7];

    float* out_xyz    = (float*)d_out;
    float* out_points = out_xyz + (size_t)BB * NPOINT * 3;

    fps_kernel<<<BB, FPS_T, 0, stream>>>(xyz, out_xyz);
    group_mlp_kernel<<<BB * NPOINT, 256, 0, stream>>>(xyz, points,
                                                      w0, b0, w1, b1, w2, b2,
                                                      out_xyz, out_points);
}

// Round 6
// 815.008 us; speedup vs baseline: 1.8780x; 1.3214x over previous
//
#include <hip/hip_runtime.h>
#include <stdint.h>

#define BB 16
#define NN 4096
#define CC 64
#define NPOINT 1024
#define KK 32
#define F1 64
#define F2 64
#define F3 128

#define FPS_T 512
#define PPT (NN / FPS_T)   // 8

// ---------------- DPP 64-lane max-reduce helpers ----------------
#if defined(__has_builtin)
#if __has_builtin(__builtin_amdgcn_update_dpp)
#define HAS_DPP 1
#endif
#endif

#ifdef HAS_DPP
template <int CTRL>
__device__ __forceinline__ unsigned long long dpp_move64(unsigned long long k) {
    int lo = __builtin_amdgcn_update_dpp(0, (int)(unsigned)k,         CTRL, 0xF, 0xF, false);
    int hi = __builtin_amdgcn_update_dpp(0, (int)(unsigned)(k >> 32), CTRL, 0xF, 0xF, false);
    return ((unsigned long long)(unsigned)hi << 32) | (unsigned)lo;
}
__device__ __forceinline__ unsigned long long wave_max_key(unsigned long long key) {
    unsigned long long o;
    o = dpp_move64<0x111>(key); if (o > key) key = o;   // row_shr:1
    o = dpp_move64<0x112>(key); if (o > key) key = o;   // row_shr:2
    o = dpp_move64<0x114>(key); if (o > key) key = o;   // row_shr:4
    o = dpp_move64<0x118>(key); if (o > key) key = o;   // row_shr:8
    o = dpp_move64<0x142>(key); if (o > key) key = o;   // row_bcast15
    o = dpp_move64<0x143>(key); if (o > key) key = o;   // row_bcast31 -> lane63 has max
    return key;
}
#else
__device__ __forceinline__ unsigned long long wave_max_key(unsigned long long key) {
#pragma unroll
    for (int off = 32; off > 0; off >>= 1) {
        unsigned long long o = __shfl_xor(key, off, 64);
        if (o > key) key = o;
    }
    return key;
}
#endif

// shared-memory arena (union of FPS and MLP layouts)
// FPS : xs[4096] ys[4096] zs[4096] (49152) | wred 2x8 u64 (128) | cbuf 24 f (96)
// MLP : gbuf 32x68 (8704) | hbuf 32x64 (8192) | pmax 8x128 (4096) | cmask 64 u64 (512) | nbr 32 i (128)
#define SMEM_BYTES 49664

__global__ __launch_bounds__(512)
void fused_kernel(const float* __restrict__ xyz,
                  const float* __restrict__ points,
                  const float* __restrict__ w0, const float* __restrict__ b0,
                  const float* __restrict__ w1, const float* __restrict__ b1,
                  const float* __restrict__ w2, const float* __restrict__ b2,
                  float* __restrict__ out_xyz,
                  float* __restrict__ out_points,
                  int* __restrict__ ctr) {
    __shared__ __align__(16) char smem[SMEM_BYTES];
    const int tid = threadIdx.x;

    if (blockIdx.x < BB) {
        // ================= FPS (blocks 0..15, resident first => no deadlock) ====
        asm volatile("s_setprio 3");   // out-issue co-resident MLP waves
        float* xs = (float*)smem;
        float* ys = xs + NN;
        float* zs = ys + NN;
        unsigned long long (*wred)[FPS_T / 64] =
            (unsigned long long (*)[FPS_T / 64])(smem + 49152);
        float* cbuf = (float*)(smem + 49280);   // 8 centroids staging (24 floats)

        const int b = blockIdx.x;
        const int lane = tid & 63, wid = tid >> 6;
        const float* __restrict__ xb = xyz + (size_t)b * (NN * 3);

        float px[PPT], py[PPT], pz[PPT], dist[PPT];
#pragma unroll
        for (int t = 0; t < PPT; ++t) {
            int p = tid + t * FPS_T;
            px[t] = xb[p * 3 + 0];
            py[t] = xb[p * 3 + 1];
            pz[t] = xb[p * 3 + 2];
            xs[p] = px[t]; ys[p] = py[t]; zs[p] = pz[t];
            dist[t] = 1e10f;
        }
        __syncthreads();

        float cx = xs[0], cy = ys[0], cz = zs[0];
        float* xo = out_xyz + (size_t)b * NPOINT * 3;

        for (int i = 0; i < NPOINT; ++i) {
            if (tid == 0) {             // stage centroid i (LDS only; cheap)
                cbuf[(i & 7) * 3 + 0] = cx;
                cbuf[(i & 7) * 3 + 1] = cy;
                cbuf[(i & 7) * 3 + 2] = cz;
            }
            float bd = -1.0f; int bp = 0;
#pragma unroll
            for (int t = 0; t < PPT; ++t) {
                float dx = __fsub_rn(px[t], cx);
                float dy = __fsub_rn(py[t], cy);
                float dz = __fsub_rn(pz[t], cz);
                float d  = __fadd_rn(__fadd_rn(__fmul_rn(dx, dx), __fmul_rn(dy, dy)),
                                     __fmul_rn(dz, dz));
                float nd = fminf(dist[t], d);
                dist[t] = nd;
                if (nd > bd) { bd = nd; bp = tid + t * FPS_T; }  // first occurrence
            }
            unsigned long long key = (((unsigned long long)__float_as_uint(bd)) << 32)
                                   | (unsigned int)(NN - 1 - bp);
            key = wave_max_key(key);
            if (lane == 63) wred[i & 1][wid] = key;
            __syncthreads();

            unsigned long long best = wred[i & 1][0];
#pragma unroll
            for (int w = 1; w < FPS_T / 64; ++w) {
                unsigned long long o = wred[i & 1][w];
                if (o > best) best = o;
            }
            int bi = (NN - 1) - (int)(best & 0xffffffffu);

            // publish 8 centroids every 8 iters; drain overlaps next iteration
            if (tid == 0 && (i & 7) == 7) {
                const float4* src = (const float4*)cbuf;
                float4* dst = (float4*)(xo + (size_t)(i - 7) * 3);
                dst[0] = src[0]; dst[1] = src[1]; dst[2] = src[2];
                dst[3] = src[3]; dst[4] = src[4]; dst[5] = src[5];
                __hip_atomic_store(&ctr[b * 16], i + 1,
                                   __ATOMIC_RELEASE, __HIP_MEMORY_SCOPE_AGENT);
            }
            cx = xs[bi]; cy = ys[bi]; cz = zs[bi];
        }
    } else {
        // ================= fused ball query + gather + MLP + maxpool ===========
        float (*gbuf)[68] = (float (*)[68])smem;                 // 32 x (67+pad)
        float (*hbuf)[F1] = (float (*)[F1])(smem + 8704);        // 32 x 64
        float (*pmax)[F3] = (float (*)[F3])(smem + 16896);       // 8 x 128
        unsigned long long* cmask = (unsigned long long*)(smem + 20992);
        int* nbr = (int*)(smem + 21504);

        const int gi = blockIdx.x - BB;
        const int s = gi >> 4;          // s-major: early blocks need early centroids
        const int b = gi & 15;
        const int g = b * NPOINT + s;
        const int f = tid & 63;
        const int wid = tid >> 6;       // 0..7

        // wait until centroid s is published (poison 0xAAAAAAAA < 0 => waits)
        if (tid == 0) {
            while (__hip_atomic_load(&ctr[b * 16], __ATOMIC_RELAXED,
                                     __HIP_MEMORY_SCOPE_AGENT) < s + 1)
                __builtin_amdgcn_s_sleep(2);
            (void)__hip_atomic_load(&ctr[b * 16], __ATOMIC_ACQUIRE,
                                    __HIP_MEMORY_SCOPE_AGENT);
        }
        __syncthreads();

        // centroid via agent-scope loads (LLC-direct; immune to stale per-XCD L2)
        unsigned int ux = __hip_atomic_load((unsigned int*)&out_xyz[(size_t)g * 3 + 0],
                                            __ATOMIC_RELAXED, __HIP_MEMORY_SCOPE_AGENT);
        unsigned int uy = __hip_atomic_load((unsigned int*)&out_xyz[(size_t)g * 3 + 1],
                                            __ATOMIC_RELAXED, __HIP_MEMORY_SCOPE_AGENT);
        unsigned int uz = __hip_atomic_load((unsigned int*)&out_xyz[(size_t)g * 3 + 2],
                                            __ATOMIC_RELAXED, __HIP_MEMORY_SCOPE_AGENT);
        const float cx = __uint_as_float(ux);
        const float cy = __uint_as_float(uy);
        const float cz = __uint_as_float(uz);

        // ---- phase A1: 8 waves scan all 4096 points ----
        {
            const float* __restrict__ xb = xyz + (size_t)b * (NN * 3);
#pragma unroll
            for (int j = 0; j < 8; ++j) {
                int chunk = wid * 8 + j;
                int p = chunk * 64 + f;
                float x = xb[p * 3 + 0];
                float y = xb[p * 3 + 1];
                float z = xb[p * 3 + 2];
                float dx = __fsub_rn(cx, x);
                float dy = __fsub_rn(cy, y);
                float dz = __fsub_rn(cz, z);
                float d2 = __fadd_rn(__fadd_rn(__fmul_rn(dx, dx), __fmul_rn(dy, dy)),
                                     __fmul_rn(dz, dz));
                unsigned long long m = __ballot(d2 <= 0.04f);  // float32(0.2*0.2)
                if (f == 0) cmask[chunk] = m;
            }
        }
        __syncthreads();

        // ---- phase A2: wave 0 — ordered compaction of the 32 smallest indices ----
        if (tid < 64) {
            unsigned long long m = cmask[tid];
            int cnt = (int)__popcll(m);
            int v = cnt;
#pragma unroll
            for (int off = 1; off < 64; off <<= 1) {
                int u = __shfl_up(v, off, 64);
                if (tid >= off) v += u;
            }
            int excl = v - cnt;
            int total = __shfl(v, 63, 64);
            unsigned long long mm = m;
            int r = excl;
            while (mm && r < KK) {
                int bpos = __ffsll(mm) - 1;
                mm &= mm - 1;
                nbr[r++] = tid * 64 + bpos;
            }
            if (total < KK) {
                unsigned long long nz = __ballot(cnt > 0);
                int fchunk = __ffsll(nz) - 1;
                unsigned long long fm = cmask[fchunk];
                int first = fchunk * 64 + __ffsll(fm) - 1;
                if (tid >= total && tid < KK) nbr[tid] = first;
            }
        }
        __syncthreads();

        // ---- phase B: gather into LDS ----
        {
            const float* __restrict__ pb = points + (size_t)b * NN * CC;
#pragma unroll
            for (int m = 0; m < 4; ++m) {
                int k = wid + 8 * m;
                int idx = nbr[k] & (NN - 1);
                gbuf[k][f] = pb[(size_t)idx * CC + f];
            }
            if (tid < 96) {
                int k = tid & 31, q = tid >> 5;
                int idx = nbr[k] & (NN - 1);
                float v = xyz[((size_t)b * NN + idx) * 3 + q];
                float cq = (q == 0) ? cx : ((q == 1) ? cy : cz);
                gbuf[k][CC + q] = __fsub_rn(v, cq);
            }
        }
        __syncthreads();

        float acc[4];

        // ---- layer 1: 67 -> 64 ----
#pragma unroll
        for (int m = 0; m < 4; ++m) acc[m] = 0.0f;
#pragma unroll 4
        for (int c4 = 0; c4 < 64; c4 += 4) {
            float wv0 = w0[(c4 + 0) * F1 + f];
            float wv1 = w0[(c4 + 1) * F1 + f];
            float wv2 = w0[(c4 + 2) * F1 + f];
            float wv3 = w0[(c4 + 3) * F1 + f];
#pragma unroll
            for (int m = 0; m < 4; ++m) {
                float4 gv = *(const float4*)&gbuf[wid + 8 * m][c4];
                acc[m] = fmaf(gv.x, wv0, acc[m]);
                acc[m] = fmaf(gv.y, wv1, acc[m]);
                acc[m] = fmaf(gv.z, wv2, acc[m]);
                acc[m] = fmaf(gv.w, wv3, acc[m]);
            }
        }
        {
            float wv0 = w0[64 * F1 + f];
            float wv1 = w0[65 * F1 + f];
            float wv2 = w0[66 * F1 + f];
#pragma unroll
            for (int m = 0; m < 4; ++m) {
                int k = wid + 8 * m;
                acc[m] = fmaf(gbuf[k][64], wv0, acc[m]);
                acc[m] = fmaf(gbuf[k][65], wv1, acc[m]);
                acc[m] = fmaf(gbuf[k][66], wv2, acc[m]);
            }
        }
        {
            float bb = b0[f];
#pragma unroll
            for (int m = 0; m < 4; ++m)
                hbuf[wid + 8 * m][f] = fmaxf(acc[m] + bb, 0.0f);
        }
        __syncthreads();

        // ---- layer 2: 64 -> 64 ----
#pragma unroll
        for (int m = 0; m < 4; ++m) acc[m] = 0.0f;
#pragma unroll 4
        for (int c4 = 0; c4 < 64; c4 += 4) {
            float wv0 = w1[(c4 + 0) * F2 + f];
            float wv1 = w1[(c4 + 1) * F2 + f];
            float wv2 = w1[(c4 + 2) * F2 + f];
            float wv3 = w1[(c4 + 3) * F2 + f];
#pragma unroll
            for (int m = 0; m < 4; ++m) {
                float4 gv = *(const float4*)&hbuf[wid + 8 * m][c4];
                acc[m] = fmaf(gv.x, wv0, acc[m]);
                acc[m] = fmaf(gv.y, wv1, acc[m]);
                acc[m] = fmaf(gv.z, wv2, acc[m]);
                acc[m] = fmaf(gv.w, wv3, acc[m]);
            }
        }
        {
            float bb = b1[f];
#pragma unroll
            for (int m = 0; m < 4; ++m)
                gbuf[wid + 8 * m][f] = fmaxf(acc[m] + bb, 0.0f);
        }
        __syncthreads();

        // ---- layer 3: 64 -> 128 + maxpool ----
        float a0[4], a1[4];
#pragma unroll
        for (int m = 0; m < 4; ++m) { a0[m] = 0.0f; a1[m] = 0.0f; }
#pragma unroll 2
        for (int c4 = 0; c4 < 64; c4 += 4) {
            float w00 = w2[(c4 + 0) * F3 + f], w10 = w2[(c4 + 0) * F3 + f + 64];
            float w01 = w2[(c4 + 1) * F3 + f], w11 = w2[(c4 + 1) * F3 + f + 64];
            float w02 = w2[(c4 + 2) * F3 + f], w12 = w2[(c4 + 2) * F3 + f + 64];
            float w03 = w2[(c4 + 3) * F3 + f], w13 = w2[(c4 + 3) * F3 + f + 64];
#pragma unroll
            for (int m = 0; m < 4; ++m) {
                float4 gv = *(const float4*)&gbuf[wid + 8 * m][c4];
                a0[m] = fmaf(gv.x, w00, a0[m]);  a1[m] = fmaf(gv.x, w10, a1[m]);
                a0[m] = fmaf(gv.y, w01, a0[m]);  a1[m] = fmaf(gv.y, w11, a1[m]);
                a0[m] = fmaf(gv.z, w02, a0[m]);  a1[m] = fmaf(gv.z, w12, a1[m]);
                a0[m] = fmaf(gv.w, w03, a0[m]);  a1[m] = fmaf(gv.w, w13, a1[m]);
            }
        }
        {
            float pm0 = -1e30f, pm1 = -1e30f;
#pragma unroll
            for (int m = 0; m < 4; ++m) {
                pm0 = fmaxf(pm0, a0[m]);
                pm1 = fmaxf(pm1, a1[m]);
            }
            pmax[wid][f] = pm0;
            pmax[wid][f + 64] = pm1;
        }
        __syncthreads();
        if (tid < F3) {
            float v = pmax[0][tid];
#pragma unroll
            for (int w = 1; w < 8; ++w) v = fmaxf(v, pmax[w][tid]);
            v = fmaxf(v + b2[tid], 0.0f);   // relu(max+b) == max(relu(+b))
            out_points[(size_t)g * F3 + tid] = v;
        }
    }
}

extern "C" void kernel_launch(void* const* d_in, const int* in_sizes, int n_in,
                              void* d_out, int out_size, void* d_ws, size_t ws_size,
                              hipStream_t stream) {
    const float* xyz    = (const float*)d_in[0];
    const float* points = (const float*)d_in[1];
    const float* w0 = (const float*)d_in[2];
    const float* b0 = (const float*)d_in[3];
    const float* w1 = (const float*)d_in[4];
    const float* b1 = (const float*)d_in[5];
    const float* w2 = (const float*)d_in[6];
    const float* b2 = (const float*)d_in[7];

    float* out_xyz    = (float*)d_out;
    float* out_points = out_xyz + (size_t)BB * NPOINT * 3;
    int*   ctr        = (int*)d_ws;   // 16 counters, 64B stride (1 KiB used)

    fused_kernel<<<BB + BB * NPOINT, 512, 0, stream>>>(
        xyz, points, w0, b0, w1, b1, w2, b2, out_xyz, out_points, ctr);
}